// Round 16
// baseline (215.791 us; speedup 1.0000x reference)
//
#include <hip/hip_runtime.h>
#include <stdint.h>

#define NNODES 1024
#define NGRAPH 128
#define TOPK   16384
#define EQCAP  4096

typedef float vfloat4 __attribute__((ext_vector_type(4)));

// Order-preserving monotone map fp32 -> u32 (larger float => larger key).
__device__ __forceinline__ uint32_t fkey(float x) {
    uint32_t u = __float_as_uint(x);
    return (u & 0x80000000u) ? ~u : (u | 0x80000000u);
}
// Exact bit-level inverse of fkey (validated R6/R9/R11).
__device__ __forceinline__ float inv_fkey(uint32_t k) {
    uint32_t u = (k & 0x80000000u) ? (k & 0x7FFFFFFFu) : ~k;
    return __uint_as_float(u);
}
// Compiler-only fence for wave-synchronous LDS (no HW cost).
__device__ __forceinline__ void wavefence() {
    __builtin_amdgcn_wave_barrier();
    asm volatile("" ::: "memory");
}
// Wave64 reduction on the VALU pipe via DPP (zero DS-pipe traffic) --
// R14-validated sequence; lane 63 holds the result. bound_ctrl=true: OOB
// lanes read 0 (identity for u32 add and u32 max).
__device__ __forceinline__ uint32_t wave_sum_dpp(uint32_t v) {
    int x = (int)v;
    x += __builtin_amdgcn_update_dpp(0, x, 0x111, 0xF, 0xF, true);  // row_shr:1
    x += __builtin_amdgcn_update_dpp(0, x, 0x112, 0xF, 0xF, true);  // row_shr:2
    x += __builtin_amdgcn_update_dpp(0, x, 0x114, 0xF, 0xF, true);  // row_shr:4
    x += __builtin_amdgcn_update_dpp(0, x, 0x118, 0xF, 0xF, true);  // row_shr:8
    x += __builtin_amdgcn_update_dpp(0, x, 0x142, 0xF, 0xF, true);  // row_bcast:15
    x += __builtin_amdgcn_update_dpp(0, x, 0x143, 0xF, 0xF, true);  // row_bcast:31
    return (uint32_t)x;
}
__device__ __forceinline__ uint32_t wave_max_dpp(uint32_t v) {
    uint32_t x = v, y;
    y = (uint32_t)__builtin_amdgcn_update_dpp(0, (int)x, 0x111, 0xF, 0xF, true); if (y > x) x = y;
    y = (uint32_t)__builtin_amdgcn_update_dpp(0, (int)x, 0x112, 0xF, 0xF, true); if (y > x) x = y;
    y = (uint32_t)__builtin_amdgcn_update_dpp(0, (int)x, 0x114, 0xF, 0xF, true); if (y > x) x = y;
    y = (uint32_t)__builtin_amdgcn_update_dpp(0, (int)x, 0x118, 0xF, 0xF, true); if (y > x) x = y;
    y = (uint32_t)__builtin_amdgcn_update_dpp(0, (int)x, 0x142, 0xF, 0xF, true); if (y > x) x = y;
    y = (uint32_t)__builtin_amdgcn_update_dpp(0, (int)x, 0x143, 0xF, 0xF, true); if (y > x) x = y;
    return x;   // lane 63 valid
}

// ---------------------------------------------------------------------------
// Fused selection kernel, one 1024-thread block per graph. R14 structure
// (best: 129.9us) with two final DS-pipe strips:
//  - sort u32 KEYS ONLY (no payload): halves sort DS bytes. Tie collection
//    no longer uses the sorted payload -- a row scans its 1024 t values
//    (L2-resident) IFF its equal-range is non-empty (expected ~0-2 rows).
//  - seed reduce via DPP max (min via ~max(~x)) -- last __shfl removed.
// Lessons encoded: select is DS-pipe/latency bound (R4/R7/R14/R15); the
// binary+interval-tracked search is latency-optimal (R7,R15: 4-ary chains
// lose); only work-strips win (R11/R13/R14), restructures lose (6-for-6).
//  - bitonic sort barrier rule (R13): barrier iff this step reads data
//    another wave wrote last step: j>=64 || (j==32 && k>64).
//  - seeded range [lb,ub] (R13): ub = max product key (cnt_gt(ub)=0 keeps
//    cntHi exact); lb = min over rows of row's 17th-largest product key.
//  - binary search w/ per-row interval tracking (R5/R14); thread 0 tracks
//    cntHi = cnt_gt(hi) -> R = K - cntHi, no final count pass.
// ---------------------------------------------------------------------------
__global__ __launch_bounds__(NNODES)
void select_kernel(const float* __restrict__ s, const float* __restrict__ t,
                   uint32_t* __restrict__ Tout, uint32_t* __restrict__ Rout,
                   uint32_t* __restrict__ eqCntG, uint32_t* __restrict__ eqIdxG) {
    const int g = blockIdx.x, i = threadIdx.x;
    __shared__ uint32_t sk[NNODES];      // t keys, sorted ascending
    __shared__ float    tvs[NNODES];     // t values in key-ascending order
    __shared__ uint32_t wsum[16], wsum2[16];
    __shared__ uint32_t sLo, sHi, sDir, sEqCnt;
    __shared__ uint32_t sEqList[EQCAP];

    const float tv_i = t[g * NNODES + i];
    sk[i] = fkey(tv_i);
    if (i == 0) sEqCnt = 0u;

    // ---- bitonic sort on u32 keys (R13 barrier rule) ----
    for (int k = 2; k <= NNODES; k <<= 1) {
        for (int j = k >> 1; j > 0; j >>= 1) {
            if ((j >= 64) || (j == 32 && k > 64)) __syncthreads();
            else                                  wavefence();
            int partner = i ^ j;
            if (partner > i) {
                bool asc = ((i & k) == 0);
                uint32_t a = sk[i], b = sk[partner];
                if ((a > b) == asc) { sk[i] = b; sk[partner] = a; }
            }
        }
    }
    __syncthreads();
    tvs[i] = inv_fkey(sk[i]);

    const float sv = s[g * NNODES + i];
    const bool sneg = (__float_as_uint(sv) >> 31) != 0;
    const uint32_t kdiag = fkey(sv * tv_i);   // diagonal element (excluded)
    __syncthreads();                          // tvs visible to all

    // ---- seed [lb, ub] (R13 bounds, DPP reduce) ----
    {
        uint32_t m = fkey(sv * tvs[sneg ? 0 : (NNODES - 1)]);    // row max key
        uint32_t n = fkey(sv * tvs[sneg ? 16 : (NNODES - 17)]);  // row 17th-largest
        m = wave_max_dpp(m);
        n = ~wave_max_dpp(~n);                                   // wave min
        if ((i & 63) == 63) { wsum[i >> 6] = m; wsum2[i >> 6] = n; }
        __syncthreads();
        if (i == 0) {
            uint32_t ub = 0u, lb = 0xFFFFFFFFu;
            for (int w = 0; w < 16; ++w) {
                if (wsum[w]  > ub) ub = wsum[w];
                if (wsum2[w] < lb) lb = wsum2[w];
            }
            sLo = lb; sHi = ub;
        }
        __syncthreads();
    }

    // boundary search within [lo_,hi_): for s>=+0 rows, (key>cand) true on
    // suffix starting at b; for s<0 rows, prefix ending at b. b monotone in cand.
    auto srchRange = [&](uint32_t cand, int lo_, int hi_) -> int {
        while (lo_ < hi_) {
            int mid = (lo_ + hi_) >> 1;
            bool pred = fkey(sv * tvs[mid]) > cand;
            bool goLeft = sneg ? !pred : pred;
            if (goLeft) hi_ = mid; else lo_ = mid + 1;
        }
        return lo_;
    };

    int rlo = 0, rhi = NNODES;       // per-row interval covering b(c), c in [sLo,sHi]
    uint32_t cntHi = 0u;             // thread 0 only: cnt_gt(sHi); exact (sHi=ub: 0)

    // ---- binary search: minimal T in [sLo,sHi] with cnt_gt(T) < K (R14) ----
    for (int it = 0; it < 33; ++it) {
        const uint32_t lo = sLo, hi = sHi;       // uniform (read after barrier)
        if (lo >= hi) break;                     // uniform early exit
        const uint32_t mid = lo + ((hi - lo) >> 1);
        const int b = srchRange(mid, rlo, rhi);
        uint32_t c = sneg ? (uint32_t)b : (uint32_t)(NNODES - b);
        if (kdiag > mid) c--;                    // exclude diagonal if it qualified
        uint32_t r = wave_sum_dpp(c);            // VALU-pipe reduce; lane 63 valid
        if ((i & 63) == 63) wsum[i >> 6] = r;
        __syncthreads();
        if (i == 0) {
            uint32_t tot = 0;
            for (int w = 0; w < 16; ++w) tot += wsum[w];
            if (tot < TOPK) { sHi = mid; sDir = 0u; cntHi = tot; }  // go left
            else            { sLo = mid + 1; sDir = 1u; }           // go right
        }
        __syncthreads();
        if (sDir == 0u) { if (!sneg) rhi = b; else rlo = b; }
        else            { if (!sneg) rlo = b; else rhi = b; }
    }
    const uint32_t T = sLo;                      // sLo==sHi; cnt_gt(T)==cntHi
    if (i == 0) { Tout[g] = T; Rout[g] = TOPK - cntHi; }

    // ---- collect ties (key == T), diagonal excluded. Equal-range existence
    //      via two binary searches; rare rows scan their t row directly ----
    auto bound = [&](bool ge) -> int {
        int lo_ = 0, hi_ = NNODES;
        while (lo_ < hi_) {
            int mid = (lo_ + hi_) >> 1;
            uint32_t k = fkey(sv * tvs[mid]);
            bool pred = ge ? (k >= T) : (k > T);
            bool goLeft = sneg ? !pred : pred;
            if (goLeft) hi_ = mid; else lo_ = mid + 1;
        }
        return lo_;
    };
    int e0, e1;
    if (!sneg) { e0 = bound(true);  e1 = bound(false); }   // equals = [ge, gt)
    else       { e0 = bound(false); e1 = bound(true);  }   // equals = [gt, ge)
    if (e1 > e0) {                                         // cold: row has ties
        const float* trow = t + (size_t)g * NNODES;
        for (int j = 0; j < NNODES; ++j) {
            if (j == i) continue;
            if (fkey(sv * trow[j]) == T) {
                uint32_t slot = atomicAdd(&sEqCnt, 1u);
                if (slot < EQCAP) sEqList[slot] = (uint32_t)(i * NNODES) + (uint32_t)j;
            }
        }
    }
    __syncthreads();
    uint32_t E = sEqCnt; if (E > EQCAP) E = EQCAP;
    if (i == 0) eqCntG[g] = E;
    for (uint32_t p = i; p < E; p += NNODES) eqIdxG[g * EQCAP + p] = sEqList[p];
}

// ---------------------------------------------------------------------------
// Output write, R5/R11-validated shape (one block per output row, one float4
// store per thread), tie resolution folded into a cold path (R10/R11).
// out = 1 iff (key>T && j!=i) or (key==T && j!=i && rank_among_ties < R).
// ---------------------------------------------------------------------------
__global__ __launch_bounds__(256)
void write_kernel(const float* __restrict__ s, const float* __restrict__ t,
                  const uint32_t* __restrict__ Tin, const uint32_t* __restrict__ Rin,
                  const uint32_t* __restrict__ eqCntG, const uint32_t* __restrict__ eqIdxG,
                  float* __restrict__ out) {
    const int b = blockIdx.x;           // g*1024 + i
    const int g = b >> 10, i = b & 1023;
    const uint32_t T = Tin[g];
    const float sv = s[(size_t)g * NNODES + i];
    const vfloat4 tv = ((const vfloat4*)(t + (size_t)g * NNODES))[threadIdx.x];
    const int j0 = threadIdx.x * 4;
    const uint32_t k0 = fkey(sv * tv.x), k1 = fkey(sv * tv.y);
    const uint32_t k2 = fkey(sv * tv.z), k3 = fkey(sv * tv.w);
    vfloat4 o;
    o.x = (k0 > T && (j0 + 0) != i) ? 1.0f : 0.0f;
    o.y = (k1 > T && (j0 + 1) != i) ? 1.0f : 0.0f;
    o.z = (k2 > T && (j0 + 2) != i) ? 1.0f : 0.0f;
    o.w = (k3 > T && (j0 + 3) != i) ? 1.0f : 0.0f;
    if (k0 == T || k1 == T || k2 == T || k3 == T) {          // cold path: ties
        uint32_t E = eqCntG[g]; if (E > EQCAP) E = EQCAP;
        const uint32_t R = Rin[g];
        const uint32_t* eq = eqIdxG + (size_t)g * EQCAP;
        const uint32_t kk[4] = {k0, k1, k2, k3};
        #pragma unroll
        for (int q = 0; q < 4; ++q) {
            const uint32_t j = j0 + q;
            if (kk[q] == T && (int)j != i) {
                const uint32_t f = (uint32_t)i * NNODES + j;
                uint32_t rank = 0;
                for (uint32_t e2 = 0; e2 < E; ++e2) rank += (eq[e2] < f) ? 1u : 0u;
                if (rank < R) ((float*)&o)[q] = 1.0f;
            }
        }
    }
    ((vfloat4*)(out + (size_t)g * NNODES * NNODES + (size_t)i * NNODES))[threadIdx.x] = o;
}

extern "C" void kernel_launch(void* const* d_in, const int* in_sizes, int n_in,
                              void* d_out, int out_size, void* d_ws, size_t ws_size,
                              hipStream_t stream) {
    // inputs: x (unused), emb_s [G,N,1], emb_t [G,1,N] -- all float32
    const float* s = (const float*)d_in[1];
    const float* t = (const float*)d_in[2];
    float* out = (float*)d_out;

    char* ws = (char*)d_ws;
    uint32_t* Tbuf  = (uint32_t*)ws; ws += (size_t)NGRAPH * 4;
    uint32_t* Rbuf  = (uint32_t*)ws; ws += (size_t)NGRAPH * 4;
    uint32_t* eqCnt = (uint32_t*)ws; ws += (size_t)NGRAPH * 4;
    uint32_t* eqIdx = (uint32_t*)ws; ws += (size_t)NGRAPH * EQCAP * 4;

    select_kernel<<<NGRAPH, NNODES, 0, stream>>>(s, t, Tbuf, Rbuf, eqCnt, eqIdx);
    write_kernel<<<NGRAPH * NNODES, 256, 0, stream>>>(s, t, Tbuf, Rbuf, eqCnt, eqIdx, out);
}

// Round 17
// 127.409 us; speedup vs baseline: 1.6937x; 1.6937x over previous
//
#include <hip/hip_runtime.h>
#include <stdint.h>

#define NNODES 1024
#define NGRAPH 128
#define TOPK   16384
#define EQCAP  4096

typedef float vfloat4 __attribute__((ext_vector_type(4)));

// Order-preserving monotone map fp32 -> u32 (larger float => larger key).
__device__ __forceinline__ uint32_t fkey(float x) {
    uint32_t u = __float_as_uint(x);
    return (u & 0x80000000u) ? ~u : (u | 0x80000000u);
}
// Exact bit-level inverse of fkey (validated R6/R9/R11).
__device__ __forceinline__ float inv_fkey(uint32_t k) {
    uint32_t u = (k & 0x80000000u) ? (k & 0x7FFFFFFFu) : ~k;
    return __uint_as_float(u);
}
// Compiler-only fence for wave-synchronous LDS (no HW cost).
__device__ __forceinline__ void wavefence() {
    __builtin_amdgcn_wave_barrier();
    asm volatile("" ::: "memory");
}
// Wave64 reductions on the VALU pipe via DPP (zero DS-pipe traffic) --
// R14-validated; lane 63 holds the result. bound_ctrl=true: OOB lanes read 0
// (identity for u32 add and u32 max).
__device__ __forceinline__ uint32_t wave_sum_dpp(uint32_t v) {
    int x = (int)v;
    x += __builtin_amdgcn_update_dpp(0, x, 0x111, 0xF, 0xF, true);  // row_shr:1
    x += __builtin_amdgcn_update_dpp(0, x, 0x112, 0xF, 0xF, true);  // row_shr:2
    x += __builtin_amdgcn_update_dpp(0, x, 0x114, 0xF, 0xF, true);  // row_shr:4
    x += __builtin_amdgcn_update_dpp(0, x, 0x118, 0xF, 0xF, true);  // row_shr:8
    x += __builtin_amdgcn_update_dpp(0, x, 0x142, 0xF, 0xF, true);  // row_bcast:15
    x += __builtin_amdgcn_update_dpp(0, x, 0x143, 0xF, 0xF, true);  // row_bcast:31
    return (uint32_t)x;
}
__device__ __forceinline__ uint32_t wave_max_dpp(uint32_t v) {
    uint32_t x = v, y;
    y = (uint32_t)__builtin_amdgcn_update_dpp(0, (int)x, 0x111, 0xF, 0xF, true); if (y > x) x = y;
    y = (uint32_t)__builtin_amdgcn_update_dpp(0, (int)x, 0x112, 0xF, 0xF, true); if (y > x) x = y;
    y = (uint32_t)__builtin_amdgcn_update_dpp(0, (int)x, 0x114, 0xF, 0xF, true); if (y > x) x = y;
    y = (uint32_t)__builtin_amdgcn_update_dpp(0, (int)x, 0x118, 0xF, 0xF, true); if (y > x) x = y;
    y = (uint32_t)__builtin_amdgcn_update_dpp(0, (int)x, 0x142, 0xF, 0xF, true); if (y > x) x = y;
    y = (uint32_t)__builtin_amdgcn_update_dpp(0, (int)x, 0x143, 0xF, 0xF, true); if (y > x) x = y;
    return x;   // lane 63 valid
}

// ---------------------------------------------------------------------------
// Fused selection kernel, one 1024-thread block per graph. R14 structure
// (session best: 129.9us) + DPP seed reduce (last __shfl removed).
// R16 lesson encoded: the u64 PAYLOAD sort is load-bearing -- tie collection
// must be O(ties) via the sorted payload; every graph has >=1 tie row (the
// K-th element itself), so any O(N) per-tie-row fallback runs every block
// (was +86us). Other lessons: select is DS-pipe/latency bound (R4/R7/R14);
// binary+interval-tracked search is latency-optimal (R7/R15: n-ary chains
// lose); strips win (R11/R13/R14), restructures lose (6-for-6).
//  - bitonic sort on packed u64 (key<<16)|idx; barrier iff this step reads
//    data another wave wrote last step: j>=64 || (j==32 && k>64)  (R13).
//  - seeded range [lb,ub] (R13): ub = max product key (cnt_gt(ub)=0 keeps
//    cntHi exact); lb = min over rows of row's 17th-largest product key
//    (>=16 non-diag elems/row above lb -> union >= K -> T >= lb).
//  - binary search w/ per-row interval tracking (R5/R14); thread 0 tracks
//    cntHi = cnt_gt(hi) -> R = K - cntHi, no final count pass.
//  - collect ties (key == T, diag excluded) from sorted payload, O(ties).
// ---------------------------------------------------------------------------
__global__ __launch_bounds__(NNODES)
void select_kernel(const float* __restrict__ s, const float* __restrict__ t,
                   uint32_t* __restrict__ Tout, uint32_t* __restrict__ Rout,
                   uint32_t* __restrict__ eqCntG, uint32_t* __restrict__ eqIdxG) {
    const int g = blockIdx.x, i = threadIdx.x;
    __shared__ uint64_t spk[NNODES];     // packed (key<<16)|idx, sorted ascending
    __shared__ float    tvs[NNODES];     // t values in key-ascending order
    __shared__ uint32_t wsum[16], wsum2[16];
    __shared__ uint32_t sLo, sHi, sDir, sEqCnt;
    __shared__ uint32_t sEqList[EQCAP];

    const float tv_i = t[g * NNODES + i];
    spk[i] = ((uint64_t)fkey(tv_i) << 16) | (uint32_t)i;
    if (i == 0) sEqCnt = 0u;

    // ---- bitonic sort on packed u64 (R13 barrier rule) ----
    for (int k = 2; k <= NNODES; k <<= 1) {
        for (int j = k >> 1; j > 0; j >>= 1) {
            if ((j >= 64) || (j == 32 && k > 64)) __syncthreads();
            else                                  wavefence();
            int partner = i ^ j;
            if (partner > i) {
                bool asc = ((i & k) == 0);
                uint64_t a = spk[i], b = spk[partner];
                if ((a > b) == asc) { spk[i] = b; spk[partner] = a; }
            }
        }
    }
    __syncthreads();
    tvs[i] = inv_fkey((uint32_t)(spk[i] >> 16));

    const float sv = s[g * NNODES + i];
    const bool sneg = (__float_as_uint(sv) >> 31) != 0;
    const uint32_t kdiag = fkey(sv * tv_i);   // diagonal element (excluded)
    __syncthreads();                          // tvs visible to all

    // ---- seed [lb, ub] (R13 bounds, DPP reduce) ----
    {
        uint32_t m = fkey(sv * tvs[sneg ? 0 : (NNODES - 1)]);    // row max key
        uint32_t n = fkey(sv * tvs[sneg ? 16 : (NNODES - 17)]);  // row 17th-largest
        m = wave_max_dpp(m);
        n = ~wave_max_dpp(~n);                                   // wave min
        if ((i & 63) == 63) { wsum[i >> 6] = m; wsum2[i >> 6] = n; }
        __syncthreads();
        if (i == 0) {
            uint32_t ub = 0u, lb = 0xFFFFFFFFu;
            for (int w = 0; w < 16; ++w) {
                if (wsum[w]  > ub) ub = wsum[w];
                if (wsum2[w] < lb) lb = wsum2[w];
            }
            sLo = lb; sHi = ub;
        }
        __syncthreads();
    }

    // boundary search within [lo_,hi_): for s>=+0 rows, (key>cand) true on
    // suffix starting at b; for s<0 rows, prefix ending at b. b monotone in cand.
    auto srchRange = [&](uint32_t cand, int lo_, int hi_) -> int {
        while (lo_ < hi_) {
            int mid = (lo_ + hi_) >> 1;
            bool pred = fkey(sv * tvs[mid]) > cand;
            bool goLeft = sneg ? !pred : pred;
            if (goLeft) hi_ = mid; else lo_ = mid + 1;
        }
        return lo_;
    };

    int rlo = 0, rhi = NNODES;       // per-row interval covering b(c), c in [sLo,sHi]
    uint32_t cntHi = 0u;             // thread 0 only: cnt_gt(sHi); exact (sHi=ub: 0)

    // ---- binary search: minimal T in [sLo,sHi] with cnt_gt(T) < K (R14) ----
    for (int it = 0; it < 33; ++it) {
        const uint32_t lo = sLo, hi = sHi;       // uniform (read after barrier)
        if (lo >= hi) break;                     // uniform early exit
        const uint32_t mid = lo + ((hi - lo) >> 1);
        const int b = srchRange(mid, rlo, rhi);
        uint32_t c = sneg ? (uint32_t)b : (uint32_t)(NNODES - b);
        if (kdiag > mid) c--;                    // exclude diagonal if it qualified
        uint32_t r = wave_sum_dpp(c);            // VALU-pipe reduce; lane 63 valid
        if ((i & 63) == 63) wsum[i >> 6] = r;
        __syncthreads();
        if (i == 0) {
            uint32_t tot = 0;
            for (int w = 0; w < 16; ++w) tot += wsum[w];
            if (tot < TOPK) { sHi = mid; sDir = 0u; cntHi = tot; }  // go left
            else            { sLo = mid + 1; sDir = 1u; }           // go right
        }
        __syncthreads();
        if (sDir == 0u) { if (!sneg) rhi = b; else rlo = b; }
        else            { if (!sneg) rlo = b; else rhi = b; }
    }
    const uint32_t T = sLo;                      // sLo==sHi; cnt_gt(T)==cntHi
    if (i == 0) { Tout[g] = T; Rout[g] = TOPK - cntHi; }

    // ---- collect ties (key == T), diagonal excluded -- O(ties) via payload ----
    auto bound = [&](bool ge) -> int {
        int lo_ = 0, hi_ = NNODES;
        while (lo_ < hi_) {
            int mid = (lo_ + hi_) >> 1;
            uint32_t k = fkey(sv * tvs[mid]);
            bool pred = ge ? (k >= T) : (k > T);
            bool goLeft = sneg ? !pred : pred;
            if (goLeft) hi_ = mid; else lo_ = mid + 1;
        }
        return lo_;
    };
    int e0, e1;
    if (!sneg) { e0 = bound(true);  e1 = bound(false); }   // equals = [ge, gt)
    else       { e0 = bound(false); e1 = bound(true);  }   // equals = [gt, ge)
    for (int p = e0; p < e1; ++p) {
        uint32_t j = (uint32_t)(spk[p] & 0xFFFFu);         // original column idx
        if ((int)j == i) continue;
        uint32_t slot = atomicAdd(&sEqCnt, 1u);
        if (slot < EQCAP) sEqList[slot] = (uint32_t)(i * NNODES) + j;
    }
    __syncthreads();
    uint32_t E = sEqCnt; if (E > EQCAP) E = EQCAP;
    if (i == 0) eqCntG[g] = E;
    for (uint32_t p = i; p < E; p += NNODES) eqIdxG[g * EQCAP + p] = sEqList[p];
}

// ---------------------------------------------------------------------------
// Output write, R5/R11-validated shape (one block per output row, one float4
// store per thread), tie resolution folded into a cold path (R10/R11).
// out = 1 iff (key>T && j!=i) or (key==T && j!=i && rank_among_ties < R).
// ---------------------------------------------------------------------------
__global__ __launch_bounds__(256)
void write_kernel(const float* __restrict__ s, const float* __restrict__ t,
                  const uint32_t* __restrict__ Tin, const uint32_t* __restrict__ Rin,
                  const uint32_t* __restrict__ eqCntG, const uint32_t* __restrict__ eqIdxG,
                  float* __restrict__ out) {
    const int b = blockIdx.x;           // g*1024 + i
    const int g = b >> 10, i = b & 1023;
    const uint32_t T = Tin[g];
    const float sv = s[(size_t)g * NNODES + i];
    const vfloat4 tv = ((const vfloat4*)(t + (size_t)g * NNODES))[threadIdx.x];
    const int j0 = threadIdx.x * 4;
    const uint32_t k0 = fkey(sv * tv.x), k1 = fkey(sv * tv.y);
    const uint32_t k2 = fkey(sv * tv.z), k3 = fkey(sv * tv.w);
    vfloat4 o;
    o.x = (k0 > T && (j0 + 0) != i) ? 1.0f : 0.0f;
    o.y = (k1 > T && (j0 + 1) != i) ? 1.0f : 0.0f;
    o.z = (k2 > T && (j0 + 2) != i) ? 1.0f : 0.0f;
    o.w = (k3 > T && (j0 + 3) != i) ? 1.0f : 0.0f;
    if (k0 == T || k1 == T || k2 == T || k3 == T) {          // cold path: ties
        uint32_t E = eqCntG[g]; if (E > EQCAP) E = EQCAP;
        const uint32_t R = Rin[g];
        const uint32_t* eq = eqIdxG + (size_t)g * EQCAP;
        const uint32_t kk[4] = {k0, k1, k2, k3};
        #pragma unroll
        for (int q = 0; q < 4; ++q) {
            const uint32_t j = j0 + q;
            if (kk[q] == T && (int)j != i) {
                const uint32_t f = (uint32_t)i * NNODES + j;
                uint32_t rank = 0;
                for (uint32_t e2 = 0; e2 < E; ++e2) rank += (eq[e2] < f) ? 1u : 0u;
                if (rank < R) ((float*)&o)[q] = 1.0f;
            }
        }
    }
    ((vfloat4*)(out + (size_t)g * NNODES * NNODES + (size_t)i * NNODES))[threadIdx.x] = o;
}

extern "C" void kernel_launch(void* const* d_in, const int* in_sizes, int n_in,
                              void* d_out, int out_size, void* d_ws, size_t ws_size,
                              hipStream_t stream) {
    // inputs: x (unused), emb_s [G,N,1], emb_t [G,1,N] -- all float32
    const float* s = (const float*)d_in[1];
    const float* t = (const float*)d_in[2];
    float* out = (float*)d_out;

    char* ws = (char*)d_ws;
    uint32_t* Tbuf  = (uint32_t*)ws; ws += (size_t)NGRAPH * 4;
    uint32_t* Rbuf  = (uint32_t*)ws; ws += (size_t)NGRAPH * 4;
    uint32_t* eqCnt = (uint32_t*)ws; ws += (size_t)NGRAPH * 4;
    uint32_t* eqIdx = (uint32_t*)ws; ws += (size_t)NGRAPH * EQCAP * 4;

    select_kernel<<<NGRAPH, NNODES, 0, stream>>>(s, t, Tbuf, Rbuf, eqCnt, eqIdx);
    write_kernel<<<NGRAPH * NNODES, 256, 0, stream>>>(s, t, Tbuf, Rbuf, eqCnt, eqIdx, out);
}